// Round 1
// 930.216 us; speedup vs baseline: 1.4387x; 1.4387x over previous
//
#include <hip/hip_runtime.h>
#include <hip/hip_bf16.h>

#define Nn 50000
#define Dd 128
#define Rr 8
#define Ee 800000
#define EDd 32
#define NR (Nn * Rr)
#define BN_EPS 1e-5f
#define NREP 16

typedef __attribute__((ext_vector_type(8))) short short8;
typedef __attribute__((ext_vector_type(4))) float floatx4;
typedef unsigned short u16;

__device__ inline float bf2f(u16 u) {
    unsigned int x = ((unsigned int)u) << 16;
    return __uint_as_float(x);
}
__device__ inline u16 f2bf(float f) {
    __hip_bfloat16 h = __float2bfloat16(f);
    return *(u16*)&h;
}

// ---------------------------------------------------------------- degree + histogram
__global__ __launch_bounds__(256) void k_deg(const int* __restrict__ node_out,
                                             const int* __restrict__ relation,
                                             const float* __restrict__ w_in,
                                             float* __restrict__ deg,
                                             int* __restrict__ cnt) {
    int e = blockIdx.x * 256 + threadIdx.x;
    if (e >= Ee) return;
    int idx = node_out[e] * Rr + relation[e];
    unsafeAtomicAdd(deg + idx, w_in[e]);
    atomicAdd(cnt + idx, 1);
}

// ---------------------------------------------------------------- 3-kernel exclusive scan
__global__ __launch_bounds__(256) void k_scan1(const int* __restrict__ cnt,
                                               int* __restrict__ base,
                                               int* __restrict__ partials) {
    __shared__ int sd[256];
    int b0 = blockIdx.x * 1024;
    int t = threadIdx.x;
    int v[4], s = 0;
    #pragma unroll
    for (int j = 0; j < 4; ++j) {
        int idx = b0 + t * 4 + j;
        v[j] = (idx < NR) ? cnt[idx] : 0;
        s += v[j];
    }
    sd[t] = s;
    __syncthreads();
    for (int off = 1; off < 256; off <<= 1) {
        int xv = (t >= off) ? sd[t - off] : 0;
        __syncthreads();
        sd[t] += xv;
        __syncthreads();
    }
    int excl = sd[t] - s;
    if (t == 255) partials[blockIdx.x] = sd[255];
    int run = excl;
    #pragma unroll
    for (int j = 0; j < 4; ++j) {
        int idx = b0 + t * 4 + j;
        if (idx < NR) base[idx] = run;
        run += v[j];
    }
}

__global__ __launch_bounds__(512) void k_scan2(int* __restrict__ partials, int n) {
    __shared__ int sd[512];
    int t = threadIdx.x;
    int own = (t < n) ? partials[t] : 0;
    sd[t] = own;
    __syncthreads();
    for (int off = 1; off < 512; off <<= 1) {
        int xv = (t >= off) ? sd[t - off] : 0;
        __syncthreads();
        sd[t] += xv;
        __syncthreads();
    }
    if (t < n) partials[t] = sd[t] - own;
}

__global__ __launch_bounds__(256) void k_scan3(int* __restrict__ base,
                                               const int* __restrict__ partials) {
    int b0 = blockIdx.x * 1024;
    int add = partials[blockIdx.x];
    int t = threadIdx.x;
    #pragma unroll
    for (int j = 0; j < 4; ++j) {
        int idx = b0 + t * 4 + j;
        if (idx < NR) base[idx] += add;
    }
}

// ---------------------------------------------------------------- scatter (counting sort)
// record: {node_in, bits(ew), edge_id, 0}
__global__ __launch_bounds__(256) void k_scatter(const int* __restrict__ node_in,
                                                 const int* __restrict__ node_out,
                                                 const int* __restrict__ relation,
                                                 const float* __restrict__ w_in,
                                                 const float* __restrict__ deg,
                                                 int* __restrict__ base,
                                                 int4* __restrict__ recs) {
    int e = blockIdx.x * 256 + threadIdx.x;
    if (e >= Ee) return;
    int idx = node_out[e] * Rr + relation[e];
    int pos = atomicAdd(base + idx, 1);
    int4 r;
    r.x = node_in[e];
    r.y = __float_as_int(w_in[e] / deg[idx]);
    r.z = e;
    r.w = 0;
    recs[pos] = r;
}

// ---------------------------------------------------------------- fp32 -> bf16 convert
__global__ __launch_bounds__(256) void k_cvt(const float* __restrict__ src,
                                             u16* __restrict__ dst, long n) {
    long i = ((long)blockIdx.x * 256 + threadIdx.x) * 4;
    if (i >= n) return;
    float4 v = *(const float4*)(src + i);
    ushort4 o;
    o.x = f2bf(v.x); o.y = f2bf(v.y); o.z = f2bf(v.z); o.w = f2bf(v.w);
    *(ushort4*)(dst + i) = o;
}

// ---------------------------------------------------------------- weight transpose
// Bt[p][n][k] bf16; p 0..7: l1_Wlin k-block p; p=8: l1_Wself; p=9: l2_Wlin; p=10: l2_Wself
__global__ __launch_bounds__(256) void k_prepB(const float* __restrict__ W1,
                                               const float* __restrict__ Ws1,
                                               const float* __restrict__ W2,
                                               const float* __restrict__ Ws2,
                                               u16* __restrict__ Bt) {
    int idx = blockIdx.x * 256 + threadIdx.x;
    if (idx >= 11 * 16384) return;
    int p = idx >> 14;
    int n = (idx >> 7) & 127;
    int k = idx & 127;
    float v;
    if (p < 8)       v = W1[((p << 7) + k) * 128 + n];
    else if (p == 8) v = Ws1[k * 128 + n];
    else if (p == 9) v = W2[k * 128 + n];
    else             v = Ws2[k * 128 + n];
    Bt[((long)p << 14) + n * 128 + k] = f2bf(v);
}

// ---------------------------------------------------------------- folded edge-weight panels, layer 1
// Wef1[q][n][k], q=0..2 (K=384 covering flat kk=0..319, stride-40 rows per p):
//  kk=q*128+k; p=kk/40; j=kk%40; j<32 -> (We1 @ Wlin1_p)[j][n]; j==32 -> (be1 @ Wlin1_p)[n]; else 0
__global__ __launch_bounds__(256) void k_prepWef1(const float* __restrict__ We,
                                                  const float* __restrict__ be,
                                                  const float* __restrict__ Wlin,
                                                  u16* __restrict__ out) {
    int idx = blockIdx.x * 256 + threadIdx.x;
    if (idx >= 3 * 16384) return;
    int n = (idx >> 7) & 127;
    int k = idx & 127;
    int kk = (idx >> 14) * 128 + k;
    int p = kk / 40, j = kk % 40;
    float acc = 0.f;
    if (kk < 320 && j < 33) {
        for (int t = 0; t < 128; ++t) {
            float m = (j < 32) ? We[j * 128 + t] : be[t];
            acc = fmaf(m, Wlin[(p * 128 + t) * 128 + n], acc);
        }
    }
    out[idx] = f2bf(acc);
}

// ---------------------------------------------------------------- folded edge-weight panel, layer 2
// Wef2[n][k], k=0..63: k<32 -> (We2 @ W2lin)[k][n]; k==32 -> (be2 @ W2lin)[n]; else 0
__global__ __launch_bounds__(256) void k_prepWef2(const float* __restrict__ We,
                                                  const float* __restrict__ be,
                                                  const float* __restrict__ Wlin,
                                                  u16* __restrict__ out) {
    int idx = blockIdx.x * 256 + threadIdx.x;
    if (idx >= 8192) return;
    int n = idx >> 6;
    int k = idx & 63;
    float acc = 0.f;
    if (k < 33) {
        for (int t = 0; t < 128; ++t) {
            float m = (k < 32) ? We[k * 128 + t] : be[t];
            acc = fmaf(m, Wlin[t * 128 + n], acc);
        }
    }
    out[idx] = f2bf(acc);
}

// ---------------------------------------------------------------- CSR aggregate, layer 1 (fused ef)
// 16-lane groups, 4 destinations per wave. Produces:
//   u[d][0:128]       = sum_e ew * src[ni]          (bf16)
//   aggef_x[d][0:40]  = {sum_e ew*ef[eid][0:32], ind(c>0), 0...}  (bf16, stride 40)
__global__ __launch_bounds__(256) void k_agg1(const u16* __restrict__ src,
                                              const int* __restrict__ base_end,
                                              const int* __restrict__ cnt,
                                              const int4* __restrict__ recs,
                                              const float* __restrict__ ef,
                                              u16* __restrict__ u,
                                              u16* __restrict__ aggef_x) {
    int gid = threadIdx.x >> 4;
    int gl = threadIdx.x & 15;
    for (long d = (long)blockIdx.x * 16 + gid; d < NR; d += (long)gridDim.x * 16) {
        int end = base_end[d];
        int c = cnt[d];
        float a[8] = {0.f, 0.f, 0.f, 0.f, 0.f, 0.f, 0.f, 0.f};
        float e0 = 0.f, e1 = 0.f;
        for (int e = end - c; e < end; ++e) {
            int4 rec = recs[e];
            float w = __int_as_float(rec.y);
            short8 xv = *(const short8*)(src + (long)rec.x * Dd + gl * 8);
            float2 fv = *(const float2*)(ef + (long)rec.z * EDd + gl * 2);
            #pragma unroll
            for (int j = 0; j < 8; ++j)
                a[j] = fmaf(w, bf2f((u16)xv[j]), a[j]);
            e0 = fmaf(w, fv.x, e0);
            e1 = fmaf(w, fv.y, e1);
        }
        short8 o;
        #pragma unroll
        for (int j = 0; j < 8; ++j) o[j] = (short)f2bf(a[j]);
        *(short8*)(u + d * Dd + gl * 8) = o;
        ushort2 ev;
        ev.x = f2bf(e0);
        ev.y = f2bf(e1);
        *(ushort2*)(aggef_x + d * 40 + gl * 2) = ev;
        if (gl < 4) {
            ushort2 t;
            t.x = (gl == 0 && c > 0) ? (u16)0x3F80 : (u16)0;  // bf16 1.0 indicator
            t.y = 0;
            *(ushort2*)(aggef_x + d * 40 + 32 + gl * 2) = t;
        }
    }
}

// ---------------------------------------------------------------- CSR aggregate, layer 2 (lean)
__global__ __launch_bounds__(256) void k_agg2(const u16* __restrict__ src,
                                              const int* __restrict__ base_end,
                                              const int* __restrict__ cnt,
                                              const int4* __restrict__ recs,
                                              u16* __restrict__ u) {
    int gid = threadIdx.x >> 4;
    int gl = threadIdx.x & 15;
    for (long d = (long)blockIdx.x * 16 + gid; d < NR; d += (long)gridDim.x * 16) {
        int end = base_end[d];
        int c = cnt[d];
        float a[8] = {0.f, 0.f, 0.f, 0.f, 0.f, 0.f, 0.f, 0.f};
        for (int e = end - c; e < end; ++e) {
            int4 rec = recs[e];
            float w = __int_as_float(rec.y);
            short8 xv = *(const short8*)(src + (long)rec.x * Dd + gl * 8);
            #pragma unroll
            for (int j = 0; j < 8; ++j)
                a[j] = fmaf(w, bf2f((u16)xv[j]), a[j]);
        }
        short8 o;
        #pragma unroll
        for (int j = 0; j < 8; ++j) o[j] = (short)f2bf(a[j]);
        *(short8*)(u + d * Dd + gl * 8) = o;
    }
}

// ---------------------------------------------------------------- MFMA GEMM layer 1
// Hpre[m] = sum_{p<8} u[m*8+p] @ Bt[p] + x[m] @ Bt[8] + aggef_x[m-flat 320] @ Wef1
__global__ __launch_bounds__(256) void k_gemm_l1(const u16* __restrict__ U,
                                                 const u16* __restrict__ Xb,
                                                 const u16* __restrict__ Bt,
                                                 const u16* __restrict__ Wef,
                                                 const u16* __restrict__ Ax,
                                                 u16* __restrict__ Hpre,
                                                 float* __restrict__ stats) {
    __shared__ u16 Bs[128 * 136];
    const int tid = threadIdx.x;
    const int wave = tid >> 6, lane = tid & 63;
    const int l15 = lane & 15, kq = lane >> 4;
    const int kq8 = kq * 8;
    const int n0w = wave * 32;
    const int m0 = blockIdx.x * 64;

    floatx4 acc[4][2];
    #pragma unroll
    for (int i = 0; i < 4; ++i)
        #pragma unroll
        for (int j = 0; j < 2; ++j)
            acc[i][j] = (floatx4){0.f, 0.f, 0.f, 0.f};

    long mb[4];
    int mrow[4];
    #pragma unroll
    for (int ti = 0; ti < 4; ++ti) {
        int m = m0 + ti * 16 + l15;
        if (m >= Nn) m = Nn - 1;
        mrow[ti] = m;
        mb[ti] = (long)m * 1024;
    }

    const int stg_n = tid >> 1, stg_h = tid & 1;

    for (int p = 0; p < 12; ++p) {
        __syncthreads();
        {
            const u16* s = (p < 9) ? (Bt + ((long)p << 14) + stg_n * 128 + stg_h * 64)
                                   : (Wef + ((long)(p - 9) << 14) + stg_n * 128 + stg_h * 64);
            u16* dptr = Bs + stg_n * 136 + stg_h * 64;
            #pragma unroll
            for (int j = 0; j < 8; ++j)
                *(uint4*)(dptr + j * 8) = *(const uint4*)(s + j * 8);
        }
        __syncthreads();

        const u16* Ap;
        long aoff[4];
        if (p < 8) {
            Ap = U;
            #pragma unroll
            for (int ti = 0; ti < 4; ++ti) aoff[ti] = mb[ti] + p * 128;
        } else if (p == 8) {
            Ap = Xb;
            #pragma unroll
            for (int ti = 0; ti < 4; ++ti) aoff[ti] = (long)mrow[ti] * 128;
        } else {
            Ap = Ax;
            #pragma unroll
            for (int ti = 0; ti < 4; ++ti) aoff[ti] = (long)mrow[ti] * 320 + (p - 9) * 128;
        }

        #pragma unroll
        for (int k0 = 0; k0 < 128; k0 += 32) {
            short8 a[4], b[2];
            #pragma unroll
            for (int ti = 0; ti < 4; ++ti)
                a[ti] = *(const short8*)(Ap + aoff[ti] + k0 + kq8);
            #pragma unroll
            for (int tj = 0; tj < 2; ++tj)
                b[tj] = *(const short8*)(Bs + (n0w + tj * 16 + l15) * 136 + k0 + kq8);
            #pragma unroll
            for (int ti = 0; ti < 4; ++ti)
                #pragma unroll
                for (int tj = 0; tj < 2; ++tj)
                    acc[ti][tj] = __builtin_amdgcn_mfma_f32_16x16x32_bf16(
                        a[ti], b[tj], acc[ti][tj], 0, 0, 0);
        }
    }

    float cs[2] = {0.f, 0.f}, cq[2] = {0.f, 0.f};
    #pragma unroll
    for (int ti = 0; ti < 4; ++ti) {
        #pragma unroll
        for (int r = 0; r < 4; ++r) {
            int m = m0 + ti * 16 + kq * 4 + r;
            if (m < Nn) {
                #pragma unroll
                for (int tj = 0; tj < 2; ++tj) {
                    float v = acc[ti][tj][r];
                    int col = n0w + tj * 16 + l15;
                    Hpre[(long)m * Dd + col] = f2bf(v);
                    cs[tj] += v;
                    cq[tj] = fmaf(v, v, cq[tj]);
                }
            }
        }
    }
    #pragma unroll
    for (int tj = 0; tj < 2; ++tj) {
        cs[tj] += __shfl_xor(cs[tj], 16, 64);
        cs[tj] += __shfl_xor(cs[tj], 32, 64);
        cq[tj] += __shfl_xor(cq[tj], 16, 64);
        cq[tj] += __shfl_xor(cq[tj], 32, 64);
    }
    if (kq == 0) {
        int rep = blockIdx.x & (NREP - 1);
        #pragma unroll
        for (int tj = 0; tj < 2; ++tj) {
            int col = n0w + tj * 16 + l15;
            unsafeAtomicAdd(stats + rep * 256 + col, cs[tj]);
            unsafeAtomicAdd(stats + rep * 256 + 128 + col, cq[tj]);
        }
    }
}

// ---------------------------------------------------------------- MFMA GEMM layer 2
// Out[r*N+n] = u[n*8+r] @ Bt2[0] + h[n] @ Bt2[1] + aggef_x[n*8+r][0:64] @ Wef2
__global__ __launch_bounds__(256) void k_gemm_l2(const u16* __restrict__ U,
                                                 const u16* __restrict__ H,
                                                 const u16* __restrict__ Bt2,
                                                 const u16* __restrict__ Wef2,
                                                 const u16* __restrict__ Ax,
                                                 float* __restrict__ Out,
                                                 float* __restrict__ stats) {
    __shared__ u16 Bs[128 * 136];
    const int tid = threadIdx.x;
    const int wave = tid >> 6, lane = tid & 63;
    const int l15 = lane & 15, kq = lane >> 4;
    const int kq8 = kq * 8;
    const int wm = wave & 1, wn = wave >> 1;
    const int n0w = wn * 64;
    const long m0 = (long)blockIdx.x * 128;

    floatx4 acc[4][4];
    #pragma unroll
    for (int i = 0; i < 4; ++i)
        #pragma unroll
        for (int j = 0; j < 4; ++j)
            acc[i][j] = (floatx4){0.f, 0.f, 0.f, 0.f};

    long aoffU[4], aoffH[4], aoffE[4];
    #pragma unroll
    for (int ti = 0; ti < 4; ++ti) {
        long mm = m0 + wm * 64 + ti * 16 + l15;
        int n = (int)(mm % Nn);
        int r = (int)(mm / Nn);
        long dd = (long)n * 8 + r;
        aoffU[ti] = dd * 128;
        aoffH[ti] = (long)n * 128;
        aoffE[ti] = dd * 40;
    }

    const int stg_n = tid >> 1, stg_h = tid & 1;

    for (int p = 0; p < 2; ++p) {
        __syncthreads();
        {
            const u16* s = Bt2 + ((long)p << 14) + stg_n * 128 + stg_h * 64;
            u16* dptr = Bs + stg_n * 136 + stg_h * 64;
            #pragma unroll
            for (int j = 0; j < 8; ++j)
                *(uint4*)(dptr + j * 8) = *(const uint4*)(s + j * 8);
        }
        __syncthreads();

        const u16* Ap = p ? H : U;
        const long* ao = p ? aoffH : aoffU;

        #pragma unroll
        for (int k0 = 0; k0 < 128; k0 += 32) {
            short8 a[4], b[4];
            #pragma unroll
            for (int ti = 0; ti < 4; ++ti)
                a[ti] = *(const short8*)(Ap + ao[ti] + k0 + kq8);
            #pragma unroll
            for (int tj = 0; tj < 4; ++tj)
                b[tj] = *(const short8*)(Bs + (n0w + tj * 16 + l15) * 136 + k0 + kq8);
            #pragma unroll
            for (int ti = 0; ti < 4; ++ti)
                #pragma unroll
                for (int tj = 0; tj < 4; ++tj)
                    acc[ti][tj] = __builtin_amdgcn_mfma_f32_16x16x32_bf16(
                        a[ti], b[tj], acc[ti][tj], 0, 0, 0);
        }
    }

    // ---- folded edge-feature panel (K = 64; rows >= 33 are zero in Wef2)
    __syncthreads();
    {
        int n = tid >> 1, kh = (tid & 1) * 32;
        const u16* s = Wef2 + n * 64 + kh;
        u16* dptr = Bs + n * 136 + kh;
        #pragma unroll
        for (int j = 0; j < 4; ++j)
            *(uint4*)(dptr + j * 8) = *(const uint4*)(s + j * 8);
    }
    __syncthreads();
    #pragma unroll
    for (int k0 = 0; k0 < 64; k0 += 32) {
        short8 a[4], b[4];
        #pragma unroll
        for (int ti = 0; ti < 4; ++ti)
            a[ti] = *(const short8*)(Ax + aoffE[ti] + k0 + kq8);
        #pragma unroll
        for (int tj = 0; tj < 4; ++tj)
            b[tj] = *(const short8*)(Bs + (n0w + tj * 16 + l15) * 136 + k0 + kq8);
        #pragma unroll
        for (int ti = 0; ti < 4; ++ti)
            #pragma unroll
            for (int tj = 0; tj < 4; ++tj)
                acc[ti][tj] = __builtin_amdgcn_mfma_f32_16x16x32_bf16(
                    a[ti], b[tj], acc[ti][tj], 0, 0, 0);
    }

    float cs[4] = {0.f, 0.f, 0.f, 0.f}, cq[4] = {0.f, 0.f, 0.f, 0.f};
    #pragma unroll
    for (int ti = 0; ti < 4; ++ti) {
        #pragma unroll
        for (int r = 0; r < 4; ++r) {
            long mm = m0 + wm * 64 + ti * 16 + kq * 4 + r;
            #pragma unroll
            for (int tj = 0; tj < 4; ++tj) {
                float v = acc[ti][tj][r];
                int col = n0w + tj * 16 + l15;
                Out[mm * Dd + col] = v;
                cs[tj] += v;
                cq[tj] = fmaf(v, v, cq[tj]);
            }
        }
    }
    #pragma unroll
    for (int tj = 0; tj < 4; ++tj) {
        cs[tj] += __shfl_xor(cs[tj], 16, 64);
        cs[tj] += __shfl_xor(cs[tj], 32, 64);
        cq[tj] += __shfl_xor(cq[tj], 16, 64);
        cq[tj] += __shfl_xor(cq[tj], 32, 64);
    }
    if (kq == 0) {
        int rep = blockIdx.x & (NREP - 1);
        #pragma unroll
        for (int tj = 0; tj < 4; ++tj) {
            int col = n0w + tj * 16 + l15;
            unsafeAtomicAdd(stats + rep * 256 + col, cs[tj]);
            unsafeAtomicAdd(stats + rep * 256 + 128 + col, cq[tj]);
        }
    }
}

// ---------------------------------------------------------------- BN apply + ReLU (bf16 in/out)
__global__ __launch_bounds__(256) void k_bn_apply_bf(u16* __restrict__ X,
                                                     const float* __restrict__ stats,
                                                     const float* __restrict__ g,
                                                     const float* __restrict__ b, int M) {
    int c = (threadIdx.x & 31) * 4;
    int rh = threadIdx.x >> 5;
    float invM = 1.0f / (float)M;
    float s[4] = {0, 0, 0, 0}, q[4] = {0, 0, 0, 0};
    for (int rep = 0; rep < NREP; ++rep) {
        float4 s4 = *(const float4*)(stats + rep * 256 + c);
        float4 q4 = *(const float4*)(stats + rep * 256 + 128 + c);
        s[0] += s4.x; s[1] += s4.y; s[2] += s4.z; s[3] += s4.w;
        q[0] += q4.x; q[1] += q4.y; q[2] += q4.z; q[3] += q4.w;
    }
    float4 g4 = *(const float4*)(g + c);
    float4 b4 = *(const float4*)(b + c);
    float gv[4] = {g4.x, g4.y, g4.z, g4.w};
    float bv[4] = {b4.x, b4.y, b4.z, b4.w};
    float sc[4], sh[4];
    #pragma unroll
    for (int j = 0; j < 4; ++j) {
        float m = s[j] * invM;
        sc[j] = gv[j] / sqrtf(q[j] * invM - m * m + BN_EPS);
        sh[j] = bv[j] - m * sc[j];
    }
    for (long r = blockIdx.x * 8 + rh; r < M; r += (long)gridDim.x * 8) {
        ushort4 v = *(ushort4*)(X + r * Dd + c);
        ushort4 o;
        o.x = f2bf(fmaxf(fmaf(bf2f(v.x), sc[0], sh[0]), 0.f));
        o.y = f2bf(fmaxf(fmaf(bf2f(v.y), sc[1], sh[1]), 0.f));
        o.z = f2bf(fmaxf(fmaf(bf2f(v.z), sc[2], sh[2]), 0.f));
        o.w = f2bf(fmaxf(fmaf(bf2f(v.w), sc[3], sh[3]), 0.f));
        *(ushort4*)(X + r * Dd + c) = o;
    }
}

// ---------------------------------------------------------------- BN apply + ReLU (fp32 in-place)
__global__ __launch_bounds__(256) void k_bn_apply_f32(float* __restrict__ X,
                                                      const float* __restrict__ stats,
                                                      const float* __restrict__ g,
                                                      const float* __restrict__ b, int M) {
    int c = (threadIdx.x & 31) * 4;
    int rh = threadIdx.x >> 5;
    float invM = 1.0f / (float)M;
    float s[4] = {0, 0, 0, 0}, q[4] = {0, 0, 0, 0};
    for (int rep = 0; rep < NREP; ++rep) {
        float4 s4 = *(const float4*)(stats + rep * 256 + c);
        float4 q4 = *(const float4*)(stats + rep * 256 + 128 + c);
        s[0] += s4.x; s[1] += s4.y; s[2] += s4.z; s[3] += s4.w;
        q[0] += q4.x; q[1] += q4.y; q[2] += q4.z; q[3] += q4.w;
    }
    float4 g4 = *(const float4*)(g + c);
    float4 b4 = *(const float4*)(b + c);
    float gv[4] = {g4.x, g4.y, g4.z, g4.w};
    float bv[4] = {b4.x, b4.y, b4.z, b4.w};
    float sc[4], sh[4];
    #pragma unroll
    for (int j = 0; j < 4; ++j) {
        float m = s[j] * invM;
        sc[j] = gv[j] / sqrtf(q[j] * invM - m * m + BN_EPS);
        sh[j] = bv[j] - m * sc[j];
    }
    for (long r = blockIdx.x * 8 + rh; r < M; r += (long)gridDim.x * 8) {
        float4 v = *(float4*)(X + r * Dd + c);
        v.x = fmaxf(fmaf(v.x, sc[0], sh[0]), 0.f);
        v.y = fmaxf(fmaf(v.y, sc[1], sh[1]), 0.f);
        v.z = fmaxf(fmaf(v.z, sc[2], sh[2]), 0.f);
        v.w = fmaxf(fmaf(v.w, sc[3], sh[3]), 0.f);
        *(float4*)(X + r * Dd + c) = v;
    }
}

// ---------------------------------------------------------------- launch
extern "C" void kernel_launch(void* const* d_in, const int* in_sizes, int n_in,
                              void* d_out, int out_size, void* d_ws, size_t ws_size,
                              hipStream_t stream) {
    const float* x            = (const float*)d_in[0];
    const int*   node_in      = (const int*)d_in[1];
    const int*   node_out     = (const int*)d_in[2];
    const int*   relation     = (const int*)d_in[3];
    const float* edge_weight  = (const float*)d_in[4];
    const float* edge_feature = (const float*)d_in[5];
    const float* l1_Wlin  = (const float*)d_in[6];
    const float* l1_Wself = (const float*)d_in[8];
    const float* l1_Wedge = (const float*)d_in[10];
    const float* l1_bedge = (const float*)d_in[11];
    const float* l1_g     = (const float*)d_in[12];
    const float* l1_b     = (const float*)d_in[13];
    const float* l2_Wlin  = (const float*)d_in[14];
    const float* l2_Wself = (const float*)d_in[16];
    const float* l2_Wedge = (const float*)d_in[18];
    const float* l2_bedge = (const float*)d_in[19];
    const float* l2_g     = (const float*)d_in[20];
    const float* l2_b     = (const float*)d_in[21];
    float* out = (float*)d_out;

    // workspace layout (~193 MB)
    u16* u_bf    = (u16*)d_ws;                        // NR*128 bf16
    u16* h       = u_bf + (long)NR * Dd;              // Nn*128 bf16
    u16* x_bf    = h + (long)Nn * Dd;                 // Nn*128 bf16
    u16* aggef_x = x_bf + (long)Nn * Dd;              // NR*40 bf16 (+128 slack)
    u16* Bt      = aggef_x + (long)NR * 40 + 128;     // 11*16384 bf16
    u16* Wef1    = Bt + 11 * 16384;                   // 3*16384 bf16
    u16* Wef2    = Wef1 + 3 * 16384;                  // 8192 bf16
    float* deg   = (float*)(Wef2 + 8192);             // NR
    int*   cnt   = (int*)(deg + NR);                  // NR
    int*   base  = cnt + NR;                          // NR
    int4*  recs  = (int4*)(base + NR);                // Ee int4
    int*   partials = (int*)(recs + Ee);              // 1024
    float* stats = (float*)(partials + 1024);         // 2*NREP*256

    const int NB1 = (NR + 1023) / 1024;               // 391

    // ---- prep
    hipMemsetAsync(deg, 0, sizeof(float) * NR, stream);
    hipMemsetAsync(cnt, 0, sizeof(int) * NR, stream);
    hipMemsetAsync(stats, 0, sizeof(float) * 2 * NREP * 256, stream);
    k_deg<<<(Ee + 255) / 256, 256, 0, stream>>>(node_out, relation, edge_weight, deg, cnt);
    k_scan1<<<NB1, 256, 0, stream>>>(cnt, base, partials);
    k_scan2<<<1, 512, 0, stream>>>(partials, NB1);
    k_scan3<<<NB1, 256, 0, stream>>>(base, partials);
    k_scatter<<<(Ee + 255) / 256, 256, 0, stream>>>(node_in, node_out, relation, edge_weight,
                                                    deg, base, recs);
    k_cvt<<<((long)Nn * Dd / 4 + 255) / 256, 256, 0, stream>>>(x, x_bf, (long)Nn * Dd);
    k_prepB<<<(11 * 16384 + 255) / 256, 256, 0, stream>>>(l1_Wlin, l1_Wself, l2_Wlin, l2_Wself, Bt);
    k_prepWef1<<<(3 * 16384 + 255) / 256, 256, 0, stream>>>(l1_Wedge, l1_bedge, l1_Wlin, Wef1);
    k_prepWef2<<<32, 256, 0, stream>>>(l2_Wedge, l2_bedge, l2_Wlin, Wef2);

    // ---- layer 1
    k_agg1<<<4096, 256, 0, stream>>>(x_bf, base, cnt, recs, edge_feature, u_bf, aggef_x);
    k_gemm_l1<<<(Nn + 63) / 64, 256, 0, stream>>>(u_bf, x_bf, Bt, Wef1, aggef_x, h, stats);
    k_bn_apply_bf<<<512, 256, 0, stream>>>(h, stats, l1_g, l1_b, Nn);

    // ---- layer 2
    k_agg2<<<4096, 256, 0, stream>>>(h, base, cnt, recs, u_bf);
    k_gemm_l2<<<NR / 128, 256, 0, stream>>>(u_bf, h, Bt + 9 * 16384, Wef2, aggef_x, out,
                                            stats + NREP * 256);
    k_bn_apply_f32<<<2048, 256, 0, stream>>>(out, stats + NREP * 256, l2_g, l2_b, NR);
}

// Round 2
// 928.487 us; speedup vs baseline: 1.4414x; 1.0019x over previous
//
#include <hip/hip_runtime.h>
#include <hip/hip_bf16.h>

#define Nn 50000
#define Dd 128
#define Rr 8
#define Ee 800000
#define EDd 32
#define NR (Nn * Rr)
#define BN_EPS 1e-5f
#define NREP 16

typedef __attribute__((ext_vector_type(8))) short short8;
typedef __attribute__((ext_vector_type(4))) float floatx4;
typedef unsigned short u16;

__device__ inline float bf2f(u16 u) {
    unsigned int x = ((unsigned int)u) << 16;
    return __uint_as_float(x);
}
__device__ inline u16 f2bf(float f) {
    __hip_bfloat16 h = __float2bfloat16(f);
    return *(u16*)&h;
}

// ---------------------------------------------------------------- degree + histogram
__global__ __launch_bounds__(256) void k_deg(const int* __restrict__ node_out,
                                             const int* __restrict__ relation,
                                             const float* __restrict__ w_in,
                                             float* __restrict__ deg,
                                             int* __restrict__ cnt) {
    int e = blockIdx.x * 256 + threadIdx.x;
    if (e >= Ee) return;
    int idx = node_out[e] * Rr + relation[e];
    unsafeAtomicAdd(deg + idx, w_in[e]);
    atomicAdd(cnt + idx, 1);
}

// ---------------------------------------------------------------- 3-kernel exclusive scan
__global__ __launch_bounds__(256) void k_scan1(const int* __restrict__ cnt,
                                               int* __restrict__ base,
                                               int* __restrict__ partials) {
    __shared__ int sd[256];
    int b0 = blockIdx.x * 1024;
    int t = threadIdx.x;
    int v[4], s = 0;
    #pragma unroll
    for (int j = 0; j < 4; ++j) {
        int idx = b0 + t * 4 + j;
        v[j] = (idx < NR) ? cnt[idx] : 0;
        s += v[j];
    }
    sd[t] = s;
    __syncthreads();
    for (int off = 1; off < 256; off <<= 1) {
        int xv = (t >= off) ? sd[t - off] : 0;
        __syncthreads();
        sd[t] += xv;
        __syncthreads();
    }
    int excl = sd[t] - s;
    if (t == 255) partials[blockIdx.x] = sd[255];
    int run = excl;
    #pragma unroll
    for (int j = 0; j < 4; ++j) {
        int idx = b0 + t * 4 + j;
        if (idx < NR) base[idx] = run;
        run += v[j];
    }
}

__global__ __launch_bounds__(512) void k_scan2(int* __restrict__ partials, int n) {
    __shared__ int sd[512];
    int t = threadIdx.x;
    int own = (t < n) ? partials[t] : 0;
    sd[t] = own;
    __syncthreads();
    for (int off = 1; off < 512; off <<= 1) {
        int xv = (t >= off) ? sd[t - off] : 0;
        __syncthreads();
        sd[t] += xv;
        __syncthreads();
    }
    if (t < n) partials[t] = sd[t] - own;
}

__global__ __launch_bounds__(256) void k_scan3(int* __restrict__ base,
                                               const int* __restrict__ partials) {
    int b0 = blockIdx.x * 1024;
    int add = partials[blockIdx.x];
    int t = threadIdx.x;
    #pragma unroll
    for (int j = 0; j < 4; ++j) {
        int idx = b0 + t * 4 + j;
        if (idx < NR) base[idx] += add;
    }
}

// ---------------------------------------------------------------- scatter (counting sort)
// record: {node_in, bits(ew), edge_id, 0}
__global__ __launch_bounds__(256) void k_scatter(const int* __restrict__ node_in,
                                                 const int* __restrict__ node_out,
                                                 const int* __restrict__ relation,
                                                 const float* __restrict__ w_in,
                                                 const float* __restrict__ deg,
                                                 int* __restrict__ base,
                                                 int4* __restrict__ recs) {
    int e = blockIdx.x * 256 + threadIdx.x;
    if (e >= Ee) return;
    int idx = node_out[e] * Rr + relation[e];
    int pos = atomicAdd(base + idx, 1);
    int4 r;
    r.x = node_in[e];
    r.y = __float_as_int(w_in[e] / deg[idx]);
    r.z = e;
    r.w = 0;
    recs[pos] = r;
}

// ---------------------------------------------------------------- fp32 -> bf16 convert
__global__ __launch_bounds__(256) void k_cvt(const float* __restrict__ src,
                                             u16* __restrict__ dst, long n) {
    long i = ((long)blockIdx.x * 256 + threadIdx.x) * 4;
    if (i >= n) return;
    float4 v = *(const float4*)(src + i);
    ushort4 o;
    o.x = f2bf(v.x); o.y = f2bf(v.y); o.z = f2bf(v.z); o.w = f2bf(v.w);
    *(ushort4*)(dst + i) = o;
}

// ---------------------------------------------------------------- weight transpose
// Bt[p][n][k] bf16; p 0..7: l1_Wlin k-block p; p=8: l1_Wself; p=9: l2_Wlin; p=10: l2_Wself
__global__ __launch_bounds__(256) void k_prepB(const float* __restrict__ W1,
                                               const float* __restrict__ Ws1,
                                               const float* __restrict__ W2,
                                               const float* __restrict__ Ws2,
                                               u16* __restrict__ Bt) {
    int idx = blockIdx.x * 256 + threadIdx.x;
    if (idx >= 11 * 16384) return;
    int p = idx >> 14;
    int n = (idx >> 7) & 127;
    int k = idx & 127;
    float v;
    if (p < 8)       v = W1[((p << 7) + k) * 128 + n];
    else if (p == 8) v = Ws1[k * 128 + n];
    else if (p == 9) v = W2[k * 128 + n];
    else             v = Ws2[k * 128 + n];
    Bt[((long)p << 14) + n * 128 + k] = f2bf(v);
}

// ---------------------------------------------------------------- folded edge-weight panels, layer 1
// Wef1[q][n][k], q=0..2 (K=384 covering flat kk=0..319, stride-40 rows per p):
//  kk=q*128+k; p=kk/40; j=kk%40; j<32 -> (We1 @ Wlin1_p)[j][n]; j==32 -> (be1 @ Wlin1_p)[n]; else 0
__global__ __launch_bounds__(256) void k_prepWef1(const float* __restrict__ We,
                                                  const float* __restrict__ be,
                                                  const float* __restrict__ Wlin,
                                                  u16* __restrict__ out) {
    int idx = blockIdx.x * 256 + threadIdx.x;
    if (idx >= 3 * 16384) return;
    int n = (idx >> 7) & 127;
    int k = idx & 127;
    int kk = (idx >> 14) * 128 + k;
    int p = kk / 40, j = kk % 40;
    float acc = 0.f;
    if (kk < 320 && j < 33) {
        for (int t = 0; t < 128; ++t) {
            float m = (j < 32) ? We[j * 128 + t] : be[t];
            acc = fmaf(m, Wlin[(p * 128 + t) * 128 + n], acc);
        }
    }
    out[idx] = f2bf(acc);
}

// ---------------------------------------------------------------- folded edge-weight panel, layer 2
// Wef2[n][k], k=0..63: k<32 -> (We2 @ W2lin)[k][n]; k==32 -> (be2 @ W2lin)[n]; else 0
__global__ __launch_bounds__(256) void k_prepWef2(const float* __restrict__ We,
                                                  const float* __restrict__ be,
                                                  const float* __restrict__ Wlin,
                                                  u16* __restrict__ out) {
    int idx = blockIdx.x * 256 + threadIdx.x;
    if (idx >= 8192) return;
    int n = idx >> 6;
    int k = idx & 63;
    float acc = 0.f;
    if (k < 33) {
        for (int t = 0; t < 128; ++t) {
            float m = (k < 32) ? We[k * 128 + t] : be[t];
            acc = fmaf(m, Wlin[t * 128 + n], acc);
        }
    }
    out[idx] = f2bf(acc);
}

// ---------------------------------------------------------------- CSR aggregate, layer 1 (fused ef)
// 16-lane groups, 4 destinations per wave, 2-edge unrolled for MLP.
__global__ __launch_bounds__(256) void k_agg1(const u16* __restrict__ src,
                                              const int* __restrict__ base_end,
                                              const int* __restrict__ cnt,
                                              const int4* __restrict__ recs,
                                              const float* __restrict__ ef,
                                              u16* __restrict__ u,
                                              u16* __restrict__ aggef_x) {
    int gid = threadIdx.x >> 4;
    int gl = threadIdx.x & 15;
    int gl8 = gl * 8, gl2 = gl * 2;
    for (long d = (long)blockIdx.x * 16 + gid; d < NR; d += (long)gridDim.x * 16) {
        int end = base_end[d];
        int c = cnt[d];
        int e = end - c;
        float a[8] = {0.f, 0.f, 0.f, 0.f, 0.f, 0.f, 0.f, 0.f};
        float e0 = 0.f, e1 = 0.f;
        for (; e + 2 <= end; e += 2) {
            int4 r0 = recs[e];
            int4 r1 = recs[e + 1];
            short8 x0 = *(const short8*)(src + (long)r0.x * Dd + gl8);
            short8 x1 = *(const short8*)(src + (long)r1.x * Dd + gl8);
            float2 f0 = *(const float2*)(ef + (long)r0.z * EDd + gl2);
            float2 f1 = *(const float2*)(ef + (long)r1.z * EDd + gl2);
            float w0 = __int_as_float(r0.y);
            float w1 = __int_as_float(r1.y);
            #pragma unroll
            for (int j = 0; j < 8; ++j) {
                a[j] = fmaf(w0, bf2f((u16)x0[j]), a[j]);
                a[j] = fmaf(w1, bf2f((u16)x1[j]), a[j]);
            }
            e0 = fmaf(w0, f0.x, e0); e0 = fmaf(w1, f1.x, e0);
            e1 = fmaf(w0, f0.y, e1); e1 = fmaf(w1, f1.y, e1);
        }
        if (e < end) {
            int4 r0 = recs[e];
            float w0 = __int_as_float(r0.y);
            short8 x0 = *(const short8*)(src + (long)r0.x * Dd + gl8);
            float2 f0 = *(const float2*)(ef + (long)r0.z * EDd + gl2);
            #pragma unroll
            for (int j = 0; j < 8; ++j)
                a[j] = fmaf(w0, bf2f((u16)x0[j]), a[j]);
            e0 = fmaf(w0, f0.x, e0);
            e1 = fmaf(w0, f0.y, e1);
        }
        short8 o;
        #pragma unroll
        for (int j = 0; j < 8; ++j) o[j] = (short)f2bf(a[j]);
        *(short8*)(u + d * Dd + gl8) = o;
        ushort2 ev;
        ev.x = f2bf(e0);
        ev.y = f2bf(e1);
        *(ushort2*)(aggef_x + d * 40 + gl2) = ev;
        if (gl < 4) {
            ushort2 t;
            t.x = (gl == 0 && c > 0) ? (u16)0x3F80 : (u16)0;  // bf16 1.0 indicator
            t.y = 0;
            *(ushort2*)(aggef_x + d * 40 + 32 + gl2) = t;
        }
    }
}

// ---------------------------------------------------------------- CSR aggregate, layer 2 (lean)
__global__ __launch_bounds__(256) void k_agg2(const u16* __restrict__ src,
                                              const int* __restrict__ base_end,
                                              const int* __restrict__ cnt,
                                              const int4* __restrict__ recs,
                                              u16* __restrict__ u) {
    int gid = threadIdx.x >> 4;
    int gl = threadIdx.x & 15;
    int gl8 = gl * 8;
    for (long d = (long)blockIdx.x * 16 + gid; d < NR; d += (long)gridDim.x * 16) {
        int end = base_end[d];
        int c = cnt[d];
        int e = end - c;
        float a[8] = {0.f, 0.f, 0.f, 0.f, 0.f, 0.f, 0.f, 0.f};
        for (; e + 2 <= end; e += 2) {
            int4 r0 = recs[e];
            int4 r1 = recs[e + 1];
            short8 x0 = *(const short8*)(src + (long)r0.x * Dd + gl8);
            short8 x1 = *(const short8*)(src + (long)r1.x * Dd + gl8);
            float w0 = __int_as_float(r0.y);
            float w1 = __int_as_float(r1.y);
            #pragma unroll
            for (int j = 0; j < 8; ++j) {
                a[j] = fmaf(w0, bf2f((u16)x0[j]), a[j]);
                a[j] = fmaf(w1, bf2f((u16)x1[j]), a[j]);
            }
        }
        if (e < end) {
            int4 r0 = recs[e];
            float w0 = __int_as_float(r0.y);
            short8 x0 = *(const short8*)(src + (long)r0.x * Dd + gl8);
            #pragma unroll
            for (int j = 0; j < 8; ++j)
                a[j] = fmaf(w0, bf2f((u16)x0[j]), a[j]);
        }
        short8 o;
        #pragma unroll
        for (int j = 0; j < 8; ++j) o[j] = (short)f2bf(a[j]);
        *(short8*)(u + d * Dd + gl8) = o;
    }
}

// ---------------------------------------------------------------- GEMM panel helpers (no LDS)
// All fragment loads for the panel are issued in one batch -> deep VMEM pipeline.
template <int NK>
__device__ __forceinline__ void l1_panel(const u16* __restrict__ Ap,
                                         const long* __restrict__ aoff,
                                         const u16* __restrict__ Bp, int br0, int br1,
                                         int kq8, floatx4 (&acc)[4][2]) {
    short8 a[4][NK], b[2][NK];
    #pragma unroll
    for (int kk = 0; kk < NK; ++kk) {
        #pragma unroll
        for (int ti = 0; ti < 4; ++ti)
            a[ti][kk] = *(const short8*)(Ap + aoff[ti] + kk * 32 + kq8);
        b[0][kk] = *(const short8*)(Bp + (long)br0 * 128 + kk * 32 + kq8);
        b[1][kk] = *(const short8*)(Bp + (long)br1 * 128 + kk * 32 + kq8);
    }
    #pragma unroll
    for (int kk = 0; kk < NK; ++kk)
        #pragma unroll
        for (int ti = 0; ti < 4; ++ti)
            #pragma unroll
            for (int tj = 0; tj < 2; ++tj)
                acc[ti][tj] = __builtin_amdgcn_mfma_f32_16x16x32_bf16(
                    a[ti][kk], b[tj][kk], acc[ti][tj], 0, 0, 0);
}

template <int NK>
__device__ __forceinline__ void l2_panel(const u16* __restrict__ Ap,
                                         const long* __restrict__ aoff,
                                         const u16* __restrict__ Bp, long bstride,
                                         const int* __restrict__ brow, int koff,
                                         int kq8, floatx4 (&acc)[4][4]) {
    short8 a[4][NK], b[4][NK];
    #pragma unroll
    for (int kk = 0; kk < NK; ++kk) {
        #pragma unroll
        for (int ti = 0; ti < 4; ++ti)
            a[ti][kk] = *(const short8*)(Ap + aoff[ti] + koff + kk * 32 + kq8);
        #pragma unroll
        for (int tj = 0; tj < 4; ++tj)
            b[tj][kk] = *(const short8*)(Bp + (long)brow[tj] * bstride + koff + kk * 32 + kq8);
    }
    #pragma unroll
    for (int kk = 0; kk < NK; ++kk)
        #pragma unroll
        for (int ti = 0; ti < 4; ++ti)
            #pragma unroll
            for (int tj = 0; tj < 4; ++tj)
                acc[ti][tj] = __builtin_amdgcn_mfma_f32_16x16x32_bf16(
                    a[ti][kk], b[tj][kk], acc[ti][tj], 0, 0, 0);
}

// ---------------------------------------------------------------- MFMA GEMM layer 1 (no LDS)
// Hpre[m] = sum_{p<8} u[m*8+p] @ Bt[p] + x[m] @ Bt[8] + aggef_x[m-flat 320] @ Wef1
__global__ __launch_bounds__(256) void k_gemm_l1(const u16* __restrict__ U,
                                                 const u16* __restrict__ Xb,
                                                 const u16* __restrict__ Bt,
                                                 const u16* __restrict__ Wef,
                                                 const u16* __restrict__ Ax,
                                                 u16* __restrict__ Hpre,
                                                 float* __restrict__ stats) {
    const int tid = threadIdx.x;
    const int wave = tid >> 6, lane = tid & 63;
    const int l15 = lane & 15, kq = lane >> 4;
    const int kq8 = kq * 8;
    const int n0w = wave * 32;
    const int m0 = blockIdx.x * 64;
    const int br0 = n0w + l15, br1 = n0w + 16 + l15;

    floatx4 acc[4][2];
    #pragma unroll
    for (int i = 0; i < 4; ++i)
        #pragma unroll
        for (int j = 0; j < 2; ++j)
            acc[i][j] = (floatx4){0.f, 0.f, 0.f, 0.f};

    long mb[4];
    int mrow[4];
    #pragma unroll
    for (int ti = 0; ti < 4; ++ti) {
        int m = m0 + ti * 16 + l15;
        if (m >= Nn) m = Nn - 1;
        mrow[ti] = m;
        mb[ti] = (long)m * 1024;
    }

    long aoff[4];
    #pragma unroll
    for (int p = 0; p < 8; ++p) {
        #pragma unroll
        for (int ti = 0; ti < 4; ++ti) aoff[ti] = mb[ti] + p * 128;
        l1_panel<4>(U, aoff, Bt + ((long)p << 14), br0, br1, kq8, acc);
    }
    #pragma unroll
    for (int ti = 0; ti < 4; ++ti) aoff[ti] = (long)mrow[ti] * 128;
    l1_panel<4>(Xb, aoff, Bt + (8L << 14), br0, br1, kq8, acc);
    #pragma unroll
    for (int q = 0; q < 2; ++q) {
        #pragma unroll
        for (int ti = 0; ti < 4; ++ti) aoff[ti] = (long)mrow[ti] * 320 + q * 128;
        l1_panel<4>(Ax, aoff, Wef + ((long)q << 14), br0, br1, kq8, acc);
    }
    #pragma unroll
    for (int ti = 0; ti < 4; ++ti) aoff[ti] = (long)mrow[ti] * 320 + 256;
    l1_panel<2>(Ax, aoff, Wef + (2L << 14), br0, br1, kq8, acc);  // rows 64..127 of q=2 are zero

    float cs[2] = {0.f, 0.f}, cq[2] = {0.f, 0.f};
    #pragma unroll
    for (int ti = 0; ti < 4; ++ti) {
        #pragma unroll
        for (int r = 0; r < 4; ++r) {
            int m = m0 + ti * 16 + kq * 4 + r;
            if (m < Nn) {
                #pragma unroll
                for (int tj = 0; tj < 2; ++tj) {
                    float v = acc[ti][tj][r];
                    int col = n0w + tj * 16 + l15;
                    Hpre[(long)m * Dd + col] = f2bf(v);
                    cs[tj] += v;
                    cq[tj] = fmaf(v, v, cq[tj]);
                }
            }
        }
    }
    #pragma unroll
    for (int tj = 0; tj < 2; ++tj) {
        cs[tj] += __shfl_xor(cs[tj], 16, 64);
        cs[tj] += __shfl_xor(cs[tj], 32, 64);
        cq[tj] += __shfl_xor(cq[tj], 16, 64);
        cq[tj] += __shfl_xor(cq[tj], 32, 64);
    }
    if (kq == 0) {
        int rep = blockIdx.x & (NREP - 1);
        #pragma unroll
        for (int tj = 0; tj < 2; ++tj) {
            int col = n0w + tj * 16 + l15;
            unsafeAtomicAdd(stats + rep * 256 + col, cs[tj]);
            unsafeAtomicAdd(stats + rep * 256 + 128 + col, cq[tj]);
        }
    }
}

// ---------------------------------------------------------------- MFMA GEMM layer 2 (no LDS)
// Out[r*N+n] = u[n*8+r] @ Bt2[0] + h[n] @ Bt2[1] + aggef_x[n*8+r][0:64] @ Wef2
__global__ __launch_bounds__(256) void k_gemm_l2(const u16* __restrict__ U,
                                                 const u16* __restrict__ H,
                                                 const u16* __restrict__ Bt2,
                                                 const u16* __restrict__ Wef2,
                                                 const u16* __restrict__ Ax,
                                                 float* __restrict__ Out,
                                                 float* __restrict__ stats) {
    const int tid = threadIdx.x;
    const int wave = tid >> 6, lane = tid & 63;
    const int l15 = lane & 15, kq = lane >> 4;
    const int kq8 = kq * 8;
    const int wm = wave & 1, wn = wave >> 1;
    const int n0w = wn * 64;
    const long m0 = (long)blockIdx.x * 128;

    int brow[4];
    #pragma unroll
    for (int tj = 0; tj < 4; ++tj) brow[tj] = n0w + tj * 16 + l15;

    floatx4 acc[4][4];
    #pragma unroll
    for (int i = 0; i < 4; ++i)
        #pragma unroll
        for (int j = 0; j < 4; ++j)
            acc[i][j] = (floatx4){0.f, 0.f, 0.f, 0.f};

    long aoffU[4], aoffH[4], aoffE[4];
    #pragma unroll
    for (int ti = 0; ti < 4; ++ti) {
        long mm = m0 + wm * 64 + ti * 16 + l15;
        int n = (int)(mm % Nn);
        int r = (int)(mm / Nn);
        long dd = (long)n * 8 + r;
        aoffU[ti] = dd * 128;
        aoffH[ti] = (long)n * 128;
        aoffE[ti] = dd * 40;
    }

    l2_panel<2>(U, aoffU, Bt2, 128, brow, 0, kq8, acc);
    l2_panel<2>(U, aoffU, Bt2, 128, brow, 64, kq8, acc);
    l2_panel<2>(H, aoffH, Bt2 + 16384, 128, brow, 0, kq8, acc);
    l2_panel<2>(H, aoffH, Bt2 + 16384, 128, brow, 64, kq8, acc);
    l2_panel<2>(Ax, aoffE, Wef2, 64, brow, 0, kq8, acc);  // Wef2 rows 33..63 zero

    float cs[4] = {0.f, 0.f, 0.f, 0.f}, cq[4] = {0.f, 0.f, 0.f, 0.f};
    #pragma unroll
    for (int ti = 0; ti < 4; ++ti) {
        #pragma unroll
        for (int r = 0; r < 4; ++r) {
            long mm = m0 + wm * 64 + ti * 16 + kq * 4 + r;
            #pragma unroll
            for (int tj = 0; tj < 4; ++tj) {
                float v = acc[ti][tj][r];
                int col = n0w + tj * 16 + l15;
                Out[mm * Dd + col] = v;
                cs[tj] += v;
                cq[tj] = fmaf(v, v, cq[tj]);
            }
        }
    }
    #pragma unroll
    for (int tj = 0; tj < 4; ++tj) {
        cs[tj] += __shfl_xor(cs[tj], 16, 64);
        cs[tj] += __shfl_xor(cs[tj], 32, 64);
        cq[tj] += __shfl_xor(cq[tj], 16, 64);
        cq[tj] += __shfl_xor(cq[tj], 32, 64);
    }
    if (kq == 0) {
        int rep = blockIdx.x & (NREP - 1);
        #pragma unroll
        for (int tj = 0; tj < 4; ++tj) {
            int col = n0w + tj * 16 + l15;
            unsafeAtomicAdd(stats + rep * 256 + col, cs[tj]);
            unsafeAtomicAdd(stats + rep * 256 + 128 + col, cq[tj]);
        }
    }
}

// ---------------------------------------------------------------- BN apply + ReLU (bf16 in/out)
__global__ __launch_bounds__(256) void k_bn_apply_bf(u16* __restrict__ X,
                                                     const float* __restrict__ stats,
                                                     const float* __restrict__ g,
                                                     const float* __restrict__ b, int M) {
    int c = (threadIdx.x & 31) * 4;
    int rh = threadIdx.x >> 5;
    float invM = 1.0f / (float)M;
    float s[4] = {0, 0, 0, 0}, q[4] = {0, 0, 0, 0};
    for (int rep = 0; rep < NREP; ++rep) {
        float4 s4 = *(const float4*)(stats + rep * 256 + c);
        float4 q4 = *(const float4*)(stats + rep * 256 + 128 + c);
        s[0] += s4.x; s[1] += s4.y; s[2] += s4.z; s[3] += s4.w;
        q[0] += q4.x; q[1] += q4.y; q[2] += q4.z; q[3] += q4.w;
    }
    float4 g4 = *(const float4*)(g + c);
    float4 b4 = *(const float4*)(b + c);
    float gv[4] = {g4.x, g4.y, g4.z, g4.w};
    float bv[4] = {b4.x, b4.y, b4.z, b4.w};
    float sc[4], sh[4];
    #pragma unroll
    for (int j = 0; j < 4; ++j) {
        float m = s[j] * invM;
        sc[j] = gv[j] / sqrtf(q[j] * invM - m * m + BN_EPS);
        sh[j] = bv[j] - m * sc[j];
    }
    for (long r = blockIdx.x * 8 + rh; r < M; r += (long)gridDim.x * 8) {
        ushort4 v = *(ushort4*)(X + r * Dd + c);
        ushort4 o;
        o.x = f2bf(fmaxf(fmaf(bf2f(v.x), sc[0], sh[0]), 0.f));
        o.y = f2bf(fmaxf(fmaf(bf2f(v.y), sc[1], sh[1]), 0.f));
        o.z = f2bf(fmaxf(fmaf(bf2f(v.z), sc[2], sh[2]), 0.f));
        o.w = f2bf(fmaxf(fmaf(bf2f(v.w), sc[3], sh[3]), 0.f));
        *(ushort4*)(X + r * Dd + c) = o;
    }
}

// ---------------------------------------------------------------- BN apply + ReLU (fp32 in-place)
__global__ __launch_bounds__(256) void k_bn_apply_f32(float* __restrict__ X,
                                                      const float* __restrict__ stats,
                                                      const float* __restrict__ g,
                                                      const float* __restrict__ b, int M) {
    int c = (threadIdx.x & 31) * 4;
    int rh = threadIdx.x >> 5;
    float invM = 1.0f / (float)M;
    float s[4] = {0, 0, 0, 0}, q[4] = {0, 0, 0, 0};
    for (int rep = 0; rep < NREP; ++rep) {
        float4 s4 = *(const float4*)(stats + rep * 256 + c);
        float4 q4 = *(const float4*)(stats + rep * 256 + 128 + c);
        s[0] += s4.x; s[1] += s4.y; s[2] += s4.z; s[3] += s4.w;
        q[0] += q4.x; q[1] += q4.y; q[2] += q4.z; q[3] += q4.w;
    }
    float4 g4 = *(const float4*)(g + c);
    float4 b4 = *(const float4*)(b + c);
    float gv[4] = {g4.x, g4.y, g4.z, g4.w};
    float bv[4] = {b4.x, b4.y, b4.z, b4.w};
    float sc[4], sh[4];
    #pragma unroll
    for (int j = 0; j < 4; ++j) {
        float m = s[j] * invM;
        sc[j] = gv[j] / sqrtf(q[j] * invM - m * m + BN_EPS);
        sh[j] = bv[j] - m * sc[j];
    }
    for (long r = blockIdx.x * 8 + rh; r < M; r += (long)gridDim.x * 8) {
        float4 v = *(float4*)(X + r * Dd + c);
        v.x = fmaxf(fmaf(v.x, sc[0], sh[0]), 0.f);
        v.y = fmaxf(fmaf(v.y, sc[1], sh[1]), 0.f);
        v.z = fmaxf(fmaf(v.z, sc[2], sh[2]), 0.f);
        v.w = fmaxf(fmaf(v.w, sc[3], sh[3]), 0.f);
        *(float4*)(X + r * Dd + c) = v;
    }
}

// ---------------------------------------------------------------- launch
extern "C" void kernel_launch(void* const* d_in, const int* in_sizes, int n_in,
                              void* d_out, int out_size, void* d_ws, size_t ws_size,
                              hipStream_t stream) {
    const float* x            = (const float*)d_in[0];
    const int*   node_in      = (const int*)d_in[1];
    const int*   node_out     = (const int*)d_in[2];
    const int*   relation     = (const int*)d_in[3];
    const float* edge_weight  = (const float*)d_in[4];
    const float* edge_feature = (const float*)d_in[5];
    const float* l1_Wlin  = (const float*)d_in[6];
    const float* l1_Wself = (const float*)d_in[8];
    const float* l1_Wedge = (const float*)d_in[10];
    const float* l1_bedge = (const float*)d_in[11];
    const float* l1_g     = (const float*)d_in[12];
    const float* l1_b     = (const float*)d_in[13];
    const float* l2_Wlin  = (const float*)d_in[14];
    const float* l2_Wself = (const float*)d_in[16];
    const float* l2_Wedge = (const float*)d_in[18];
    const float* l2_bedge = (const float*)d_in[19];
    const float* l2_g     = (const float*)d_in[20];
    const float* l2_b     = (const float*)d_in[21];
    float* out = (float*)d_out;

    // workspace layout (~193 MB)
    u16* u_bf    = (u16*)d_ws;                        // NR*128 bf16
    u16* h       = u_bf + (long)NR * Dd;              // Nn*128 bf16
    u16* x_bf    = h + (long)Nn * Dd;                 // Nn*128 bf16
    u16* aggef_x = x_bf + (long)Nn * Dd;              // NR*40 bf16 (+128 slack)
    u16* Bt      = aggef_x + (long)NR * 40 + 128;     // 11*16384 bf16
    u16* Wef1    = Bt + 11 * 16384;                   // 3*16384 bf16
    u16* Wef2    = Wef1 + 3 * 16384;                  // 8192 bf16
    float* deg   = (float*)(Wef2 + 8192);             // NR
    int*   cnt   = (int*)(deg + NR);                  // NR
    int*   base  = cnt + NR;                          // NR
    int4*  recs  = (int4*)(base + NR);                // Ee int4
    int*   partials = (int*)(recs + Ee);              // 1024
    float* stats = (float*)(partials + 1024);         // 2*NREP*256

    const int NB1 = (NR + 1023) / 1024;               // 391

    // ---- prep
    hipMemsetAsync(deg, 0, sizeof(float) * NR, stream);
    hipMemsetAsync(cnt, 0, sizeof(int) * NR, stream);
    hipMemsetAsync(stats, 0, sizeof(float) * 2 * NREP * 256, stream);
    hipMemsetAsync(aggef_x + (long)NR * 40, 0, 256, stream);  // slack read by l2 tail panel
    k_deg<<<(Ee + 255) / 256, 256, 0, stream>>>(node_out, relation, edge_weight, deg, cnt);
    k_scan1<<<NB1, 256, 0, stream>>>(cnt, base, partials);
    k_scan2<<<1, 512, 0, stream>>>(partials, NB1);
    k_scan3<<<NB1, 256, 0, stream>>>(base, partials);
    k_scatter<<<(Ee + 255) / 256, 256, 0, stream>>>(node_in, node_out, relation, edge_weight,
                                                    deg, base, recs);
    k_cvt<<<((long)Nn * Dd / 4 + 255) / 256, 256, 0, stream>>>(x, x_bf, (long)Nn * Dd);
    k_prepB<<<(11 * 16384 + 255) / 256, 256, 0, stream>>>(l1_Wlin, l1_Wself, l2_Wlin, l2_Wself, Bt);
    k_prepWef1<<<(3 * 16384 + 255) / 256, 256, 0, stream>>>(l1_Wedge, l1_bedge, l1_Wlin, Wef1);
    k_prepWef2<<<32, 256, 0, stream>>>(l2_Wedge, l2_bedge, l2_Wlin, Wef2);

    // ---- layer 1
    k_agg1<<<4096, 256, 0, stream>>>(x_bf, base, cnt, recs, edge_feature, u_bf, aggef_x);
    k_gemm_l1<<<(Nn + 63) / 64, 256, 0, stream>>>(u_bf, x_bf, Bt, Wef1, aggef_x, h, stats);
    k_bn_apply_bf<<<512, 256, 0, stream>>>(h, stats, l1_g, l1_b, Nn);

    // ---- layer 2
    k_agg2<<<4096, 256, 0, stream>>>(h, base, cnt, recs, u_bf);
    k_gemm_l2<<<NR / 128, 256, 0, stream>>>(u_bf, h, Bt + 9 * 16384, Wef2, aggef_x, out,
                                            stats + NREP * 256);
    k_bn_apply_f32<<<2048, 256, 0, stream>>>(out, stats + NREP * 256, l2_g, l2_b, NR);
}

// Round 3
// 865.984 us; speedup vs baseline: 1.5455x; 1.0722x over previous
//
#include <hip/hip_runtime.h>
#include <hip/hip_bf16.h>

#define Nn 50000
#define Dd 128
#define Rr 8
#define Ee 800000
#define EDd 32
#define NR (Nn * Rr)
#define BN_EPS 1e-5f
#define NREP 16

typedef __attribute__((ext_vector_type(8))) short short8;
typedef __attribute__((ext_vector_type(4))) float floatx4;
typedef unsigned short u16;

__device__ inline float bf2f(u16 u) {
    unsigned int x = ((unsigned int)u) << 16;
    return __uint_as_float(x);
}
__device__ inline u16 f2bf(float f) {
    __hip_bfloat16 h = __float2bfloat16(f);
    return *(u16*)&h;
}
__device__ inline u16 f2h(float f) {
    _Float16 h = (_Float16)f;
    return *(u16*)&h;
}
__device__ inline float h2f(u16 u) {
    _Float16 h = *(_Float16*)&u;
    return (float)h;
}

// ---------------------------------------------------------------- degree + histogram
__global__ __launch_bounds__(256) void k_deg(const int* __restrict__ node_out,
                                             const int* __restrict__ relation,
                                             const float* __restrict__ w_in,
                                             float* __restrict__ deg,
                                             int* __restrict__ cnt) {
    int e = blockIdx.x * 256 + threadIdx.x;
    if (e >= Ee) return;
    int idx = node_out[e] * Rr + relation[e];
    unsafeAtomicAdd(deg + idx, w_in[e]);
    atomicAdd(cnt + idx, 1);
}

// ---------------------------------------------------------------- 3-kernel exclusive scan
__global__ __launch_bounds__(256) void k_scan1(const int* __restrict__ cnt,
                                               int* __restrict__ base,
                                               int* __restrict__ partials) {
    __shared__ int sd[256];
    int b0 = blockIdx.x * 1024;
    int t = threadIdx.x;
    int v[4], s = 0;
    #pragma unroll
    for (int j = 0; j < 4; ++j) {
        int idx = b0 + t * 4 + j;
        v[j] = (idx < NR) ? cnt[idx] : 0;
        s += v[j];
    }
    sd[t] = s;
    __syncthreads();
    for (int off = 1; off < 256; off <<= 1) {
        int xv = (t >= off) ? sd[t - off] : 0;
        __syncthreads();
        sd[t] += xv;
        __syncthreads();
    }
    int excl = sd[t] - s;
    if (t == 255) partials[blockIdx.x] = sd[255];
    int run = excl;
    #pragma unroll
    for (int j = 0; j < 4; ++j) {
        int idx = b0 + t * 4 + j;
        if (idx < NR) base[idx] = run;
        run += v[j];
    }
}

__global__ __launch_bounds__(512) void k_scan2(int* __restrict__ partials, int n) {
    __shared__ int sd[512];
    int t = threadIdx.x;
    int own = (t < n) ? partials[t] : 0;
    sd[t] = own;
    __syncthreads();
    for (int off = 1; off < 512; off <<= 1) {
        int xv = (t >= off) ? sd[t - off] : 0;
        __syncthreads();
        sd[t] += xv;
        __syncthreads();
    }
    if (t < n) partials[t] = sd[t] - own;
}

__global__ __launch_bounds__(256) void k_scan3(int* __restrict__ base,
                                               const int* __restrict__ partials) {
    int b0 = blockIdx.x * 1024;
    int add = partials[blockIdx.x];
    int t = threadIdx.x;
    #pragma unroll
    for (int j = 0; j < 4; ++j) {
        int idx = b0 + t * 4 + j;
        if (idx < NR) base[idx] += add;
    }
}

// ---------------------------------------------------------------- scatter (counting sort)
// record: {node_in, bits(ew), edge_id, 0}
__global__ __launch_bounds__(256) void k_scatter(const int* __restrict__ node_in,
                                                 const int* __restrict__ node_out,
                                                 const int* __restrict__ relation,
                                                 const float* __restrict__ w_in,
                                                 const float* __restrict__ deg,
                                                 int* __restrict__ base,
                                                 int4* __restrict__ recs) {
    int e = blockIdx.x * 256 + threadIdx.x;
    if (e >= Ee) return;
    int idx = node_out[e] * Rr + relation[e];
    int pos = atomicAdd(base + idx, 1);
    int4 r;
    r.x = node_in[e];
    r.y = __float_as_int(w_in[e] / deg[idx]);
    r.z = e;
    r.w = 0;
    recs[pos] = r;
}

// ---------------------------------------------------------------- fp32 -> bf16 convert
__global__ __launch_bounds__(256) void k_cvt(const float* __restrict__ src,
                                             u16* __restrict__ dst, long n) {
    long i = ((long)blockIdx.x * 256 + threadIdx.x) * 4;
    if (i >= n) return;
    float4 v = *(const float4*)(src + i);
    ushort4 o;
    o.x = f2bf(v.x); o.y = f2bf(v.y); o.z = f2bf(v.z); o.w = f2bf(v.w);
    *(ushort4*)(dst + i) = o;
}

// ---------------------------------------------------------------- weight transpose
// Bt[p][n][k] bf16; p 0..7: l1_Wlin k-block p; p=8: l1_Wself; p=9: l2_Wlin; p=10: l2_Wself
__global__ __launch_bounds__(256) void k_prepB(const float* __restrict__ W1,
                                               const float* __restrict__ Ws1,
                                               const float* __restrict__ W2,
                                               const float* __restrict__ Ws2,
                                               u16* __restrict__ Bt) {
    int idx = blockIdx.x * 256 + threadIdx.x;
    if (idx >= 11 * 16384) return;
    int p = idx >> 14;
    int n = (idx >> 7) & 127;
    int k = idx & 127;
    float v;
    if (p < 8)       v = W1[((p << 7) + k) * 128 + n];
    else if (p == 8) v = Ws1[k * 128 + n];
    else if (p == 9) v = W2[k * 128 + n];
    else             v = Ws2[k * 128 + n];
    Bt[((long)p << 14) + n * 128 + k] = f2bf(v);
}

// ---------------------------------------------------------------- folded edge-weight panels, layer 1
__global__ __launch_bounds__(256) void k_prepWef1(const float* __restrict__ We,
                                                  const float* __restrict__ be,
                                                  const float* __restrict__ Wlin,
                                                  u16* __restrict__ out) {
    int idx = blockIdx.x * 256 + threadIdx.x;
    if (idx >= 3 * 16384) return;
    int n = (idx >> 7) & 127;
    int k = idx & 127;
    int kk = (idx >> 14) * 128 + k;
    int p = kk / 40, j = kk % 40;
    float acc = 0.f;
    if (kk < 320 && j < 33) {
        for (int t = 0; t < 128; ++t) {
            float m = (j < 32) ? We[j * 128 + t] : be[t];
            acc = fmaf(m, Wlin[(p * 128 + t) * 128 + n], acc);
        }
    }
    out[idx] = f2bf(acc);
}

// ---------------------------------------------------------------- folded edge-weight panel, layer 2
// Wef2[n][k], k=0..63: k<32 -> (We2 @ W2lin)[k][n]; k==32 -> (be2 @ W2lin)[n]; else 0
__global__ __launch_bounds__(256) void k_prepWef2(const float* __restrict__ We,
                                                  const float* __restrict__ be,
                                                  const float* __restrict__ Wlin,
                                                  u16* __restrict__ out) {
    int idx = blockIdx.x * 256 + threadIdx.x;
    if (idx >= 8192) return;
    int n = idx >> 6;
    int k = idx & 63;
    float acc = 0.f;
    if (k < 33) {
        for (int t = 0; t < 128; ++t) {
            float m = (k < 32) ? We[k * 128 + t] : be[t];
            acc = fmaf(m, Wlin[t * 128 + n], acc);
        }
    }
    out[idx] = f2bf(acc);
}

// ---------------------------------------------------------------- CSR aggregate, layer 1 (fused ef)
// 16-lane groups, 4 destinations per wave, 4/2/1 cascade edge unroll.
__global__ __launch_bounds__(256) void k_agg1(const u16* __restrict__ src,
                                              const int* __restrict__ base_end,
                                              const int* __restrict__ cnt,
                                              const int4* __restrict__ recs,
                                              const float* __restrict__ ef,
                                              u16* __restrict__ u,
                                              u16* __restrict__ aggef_x) {
    int gid = threadIdx.x >> 4;
    int gl = threadIdx.x & 15;
    int gl8 = gl * 8, gl2 = gl * 2;
    for (long d = (long)blockIdx.x * 16 + gid; d < NR; d += (long)gridDim.x * 16) {
        int end = base_end[d];
        int c = cnt[d];
        int e = end - c;
        float a[8] = {0.f, 0.f, 0.f, 0.f, 0.f, 0.f, 0.f, 0.f};
        float e0 = 0.f, e1 = 0.f;
        for (; e + 4 <= end; e += 4) {
            int4 r0 = recs[e],     r1 = recs[e + 1];
            int4 r2 = recs[e + 2], r3 = recs[e + 3];
            short8 x0 = *(const short8*)(src + (long)r0.x * Dd + gl8);
            short8 x1 = *(const short8*)(src + (long)r1.x * Dd + gl8);
            short8 x2 = *(const short8*)(src + (long)r2.x * Dd + gl8);
            short8 x3 = *(const short8*)(src + (long)r3.x * Dd + gl8);
            float2 f0 = *(const float2*)(ef + (long)r0.z * EDd + gl2);
            float2 f1 = *(const float2*)(ef + (long)r1.z * EDd + gl2);
            float2 f2 = *(const float2*)(ef + (long)r2.z * EDd + gl2);
            float2 f3 = *(const float2*)(ef + (long)r3.z * EDd + gl2);
            float w0 = __int_as_float(r0.y), w1 = __int_as_float(r1.y);
            float w2 = __int_as_float(r2.y), w3 = __int_as_float(r3.y);
            #pragma unroll
            for (int j = 0; j < 8; ++j) {
                a[j] = fmaf(w0, bf2f((u16)x0[j]), a[j]);
                a[j] = fmaf(w1, bf2f((u16)x1[j]), a[j]);
                a[j] = fmaf(w2, bf2f((u16)x2[j]), a[j]);
                a[j] = fmaf(w3, bf2f((u16)x3[j]), a[j]);
            }
            e0 = fmaf(w0, f0.x, e0); e0 = fmaf(w1, f1.x, e0);
            e0 = fmaf(w2, f2.x, e0); e0 = fmaf(w3, f3.x, e0);
            e1 = fmaf(w0, f0.y, e1); e1 = fmaf(w1, f1.y, e1);
            e1 = fmaf(w2, f2.y, e1); e1 = fmaf(w3, f3.y, e1);
        }
        if (e + 2 <= end) {
            int4 r0 = recs[e], r1 = recs[e + 1];
            short8 x0 = *(const short8*)(src + (long)r0.x * Dd + gl8);
            short8 x1 = *(const short8*)(src + (long)r1.x * Dd + gl8);
            float2 f0 = *(const float2*)(ef + (long)r0.z * EDd + gl2);
            float2 f1 = *(const float2*)(ef + (long)r1.z * EDd + gl2);
            float w0 = __int_as_float(r0.y), w1 = __int_as_float(r1.y);
            #pragma unroll
            for (int j = 0; j < 8; ++j) {
                a[j] = fmaf(w0, bf2f((u16)x0[j]), a[j]);
                a[j] = fmaf(w1, bf2f((u16)x1[j]), a[j]);
            }
            e0 = fmaf(w0, f0.x, e0); e0 = fmaf(w1, f1.x, e0);
            e1 = fmaf(w0, f0.y, e1); e1 = fmaf(w1, f1.y, e1);
            e += 2;
        }
        if (e < end) {
            int4 r0 = recs[e];
            float w0 = __int_as_float(r0.y);
            short8 x0 = *(const short8*)(src + (long)r0.x * Dd + gl8);
            float2 f0 = *(const float2*)(ef + (long)r0.z * EDd + gl2);
            #pragma unroll
            for (int j = 0; j < 8; ++j)
                a[j] = fmaf(w0, bf2f((u16)x0[j]), a[j]);
            e0 = fmaf(w0, f0.x, e0);
            e1 = fmaf(w0, f0.y, e1);
        }
        short8 o;
        #pragma unroll
        for (int j = 0; j < 8; ++j) o[j] = (short)f2bf(a[j]);
        *(short8*)(u + d * Dd + gl8) = o;
        ushort2 ev;
        ev.x = f2bf(e0);
        ev.y = f2bf(e1);
        *(ushort2*)(aggef_x + d * 40 + gl2) = ev;
        if (gl < 4) {
            ushort2 t;
            t.x = (gl == 0 && c > 0) ? (u16)0x3F80 : (u16)0;  // bf16 1.0 indicator
            t.y = 0;
            *(ushort2*)(aggef_x + d * 40 + 32 + gl2) = t;
        }
    }
}

// ---------------------------------------------------------------- GEMM panel helpers (no LDS)
template <int NK>
__device__ __forceinline__ void l1_panel(const u16* __restrict__ Ap,
                                         const long* __restrict__ aoff,
                                         const u16* __restrict__ Bp, int br0, int br1,
                                         int kq8, floatx4 (&acc)[4][2]) {
    short8 a[4][NK], b[2][NK];
    #pragma unroll
    for (int kk = 0; kk < NK; ++kk) {
        #pragma unroll
        for (int ti = 0; ti < 4; ++ti)
            a[ti][kk] = *(const short8*)(Ap + aoff[ti] + kk * 32 + kq8);
        b[0][kk] = *(const short8*)(Bp + (long)br0 * 128 + kk * 32 + kq8);
        b[1][kk] = *(const short8*)(Bp + (long)br1 * 128 + kk * 32 + kq8);
    }
    #pragma unroll
    for (int kk = 0; kk < NK; ++kk)
        #pragma unroll
        for (int ti = 0; ti < 4; ++ti)
            #pragma unroll
            for (int tj = 0; tj < 2; ++tj)
                acc[ti][tj] = __builtin_amdgcn_mfma_f32_16x16x32_bf16(
                    a[ti][kk], b[tj][kk], acc[ti][tj], 0, 0, 0);
}

template <int NK>
__device__ __forceinline__ void l2_panel(const u16* __restrict__ Ap,
                                         const long* __restrict__ aoff,
                                         const u16* __restrict__ Bp, long bstride,
                                         const int* __restrict__ brow, int koff,
                                         int kq8, floatx4 (&acc)[4][4]) {
    short8 a[4][NK], b[4][NK];
    #pragma unroll
    for (int kk = 0; kk < NK; ++kk) {
        #pragma unroll
        for (int ti = 0; ti < 4; ++ti)
            a[ti][kk] = *(const short8*)(Ap + aoff[ti] + koff + kk * 32 + kq8);
        #pragma unroll
        for (int tj = 0; tj < 4; ++tj)
            b[tj][kk] = *(const short8*)(Bp + (long)brow[tj] * bstride + koff + kk * 32 + kq8);
    }
    #pragma unroll
    for (int kk = 0; kk < NK; ++kk)
        #pragma unroll
        for (int ti = 0; ti < 4; ++ti)
            #pragma unroll
            for (int tj = 0; tj < 4; ++tj)
                acc[ti][tj] = __builtin_amdgcn_mfma_f32_16x16x32_bf16(
                    a[ti][kk], b[tj][kk], acc[ti][tj], 0, 0, 0);
}

// ---------------------------------------------------------------- MFMA GEMM layer 1 (no LDS)
// Hpre[m] = sum_{p<8} u[m*8+p] @ Bt[p] + x[m] @ Bt[8] + aggef_x[m-flat 320] @ Wef1
__global__ __launch_bounds__(256) void k_gemm_l1(const u16* __restrict__ U,
                                                 const u16* __restrict__ Xb,
                                                 const u16* __restrict__ Bt,
                                                 const u16* __restrict__ Wef,
                                                 const u16* __restrict__ Ax,
                                                 u16* __restrict__ Hpre,
                                                 float* __restrict__ stats) {
    const int tid = threadIdx.x;
    const int wave = tid >> 6, lane = tid & 63;
    const int l15 = lane & 15, kq = lane >> 4;
    const int kq8 = kq * 8;
    const int n0w = wave * 32;
    const int m0 = blockIdx.x * 64;
    const int br0 = n0w + l15, br1 = n0w + 16 + l15;

    floatx4 acc[4][2];
    #pragma unroll
    for (int i = 0; i < 4; ++i)
        #pragma unroll
        for (int j = 0; j < 2; ++j)
            acc[i][j] = (floatx4){0.f, 0.f, 0.f, 0.f};

    long mb[4];
    int mrow[4];
    #pragma unroll
    for (int ti = 0; ti < 4; ++ti) {
        int m = m0 + ti * 16 + l15;
        if (m >= Nn) m = Nn - 1;
        mrow[ti] = m;
        mb[ti] = (long)m * 1024;
    }

    long aoff[4];
    #pragma unroll
    for (int p = 0; p < 8; ++p) {
        #pragma unroll
        for (int ti = 0; ti < 4; ++ti) aoff[ti] = mb[ti] + p * 128;
        l1_panel<4>(U, aoff, Bt + ((long)p << 14), br0, br1, kq8, acc);
    }
    #pragma unroll
    for (int ti = 0; ti < 4; ++ti) aoff[ti] = (long)mrow[ti] * 128;
    l1_panel<4>(Xb, aoff, Bt + (8L << 14), br0, br1, kq8, acc);
    #pragma unroll
    for (int q = 0; q < 2; ++q) {
        #pragma unroll
        for (int ti = 0; ti < 4; ++ti) aoff[ti] = (long)mrow[ti] * 320 + q * 128;
        l1_panel<4>(Ax, aoff, Wef + ((long)q << 14), br0, br1, kq8, acc);
    }
    #pragma unroll
    for (int ti = 0; ti < 4; ++ti) aoff[ti] = (long)mrow[ti] * 320 + 256;
    l1_panel<2>(Ax, aoff, Wef + (2L << 14), br0, br1, kq8, acc);  // rows 64..127 of q=2 are zero

    float cs[2] = {0.f, 0.f}, cq[2] = {0.f, 0.f};
    #pragma unroll
    for (int ti = 0; ti < 4; ++ti) {
        #pragma unroll
        for (int r = 0; r < 4; ++r) {
            int m = m0 + ti * 16 + kq * 4 + r;
            if (m < Nn) {
                #pragma unroll
                for (int tj = 0; tj < 2; ++tj) {
                    float v = acc[ti][tj][r];
                    int col = n0w + tj * 16 + l15;
                    Hpre[(long)m * Dd + col] = f2bf(v);
                    cs[tj] += v;
                    cq[tj] = fmaf(v, v, cq[tj]);
                }
            }
        }
    }
    #pragma unroll
    for (int tj = 0; tj < 2; ++tj) {
        cs[tj] += __shfl_xor(cs[tj], 16, 64);
        cs[tj] += __shfl_xor(cs[tj], 32, 64);
        cq[tj] += __shfl_xor(cq[tj], 16, 64);
        cq[tj] += __shfl_xor(cq[tj], 32, 64);
    }
    if (kq == 0) {
        int rep = blockIdx.x & (NREP - 1);
        #pragma unroll
        for (int tj = 0; tj < 2; ++tj) {
            int col = n0w + tj * 16 + l15;
            unsafeAtomicAdd(stats + rep * 256 + col, cs[tj]);
            unsafeAtomicAdd(stats + rep * 256 + 128 + col, cq[tj]);
        }
    }
}

// ---------------------------------------------------------------- layer-2 pre-transforms
// ht[n] = h[n] @ Wlin2 (Bt[9]); hsp[n] = h[n] @ Wself2 (Bt[10]); bf16 out
__global__ __launch_bounds__(256) void k_gemm_ht(const u16* __restrict__ H,
                                                 const u16* __restrict__ Bt,
                                                 u16* __restrict__ ht,
                                                 u16* __restrict__ hsp) {
    const int tid = threadIdx.x;
    const int wave = tid >> 6, lane = tid & 63;
    const int l15 = lane & 15, kq = lane >> 4;
    const int kq8 = kq * 8;
    const int n0w = wave * 32;
    const int m0 = blockIdx.x * 64;
    const int br0 = n0w + l15, br1 = n0w + 16 + l15;

    long aoff[4];
    #pragma unroll
    for (int ti = 0; ti < 4; ++ti) {
        int m = m0 + ti * 16 + l15;
        if (m >= Nn) m = Nn - 1;
        aoff[ti] = (long)m * 128;
    }

    #pragma unroll
    for (int which = 0; which < 2; ++which) {
        floatx4 acc[4][2];
        #pragma unroll
        for (int i = 0; i < 4; ++i)
            #pragma unroll
            for (int j = 0; j < 2; ++j)
                acc[i][j] = (floatx4){0.f, 0.f, 0.f, 0.f};
        l1_panel<4>(H, aoff, Bt + ((long)(9 + which) << 14), br0, br1, kq8, acc);
        u16* dst = which ? hsp : ht;
        #pragma unroll
        for (int ti = 0; ti < 4; ++ti) {
            #pragma unroll
            for (int r = 0; r < 4; ++r) {
                int m = m0 + ti * 16 + kq * 4 + r;
                if (m < Nn) {
                    #pragma unroll
                    for (int tj = 0; tj < 2; ++tj)
                        dst[(long)m * Dd + n0w + tj * 16 + l15] = f2bf(acc[ti][tj][r]);
                }
            }
        }
    }
}

// ---------------------------------------------------------------- agf2[d] = aggef_x[d][0:64] @ Wef2 (fp16 out)
__global__ __launch_bounds__(256) void k_gemm_agf2(const u16* __restrict__ Ax,
                                                   const u16* __restrict__ Wef2,
                                                   u16* __restrict__ agf2) {
    const int tid = threadIdx.x;
    const int wave = tid >> 6, lane = tid & 63;
    const int l15 = lane & 15, kq = lane >> 4;
    const int kq8 = kq * 8;
    const int wm = wave & 1, wn = wave >> 1;
    const int n0w = wn * 64;
    const long m0 = (long)blockIdx.x * 128;

    int brow[4];
    #pragma unroll
    for (int tj = 0; tj < 4; ++tj) brow[tj] = n0w + tj * 16 + l15;

    floatx4 acc[4][4];
    #pragma unroll
    for (int i = 0; i < 4; ++i)
        #pragma unroll
        for (int j = 0; j < 4; ++j)
            acc[i][j] = (floatx4){0.f, 0.f, 0.f, 0.f};

    long aoffE[4];
    #pragma unroll
    for (int ti = 0; ti < 4; ++ti)
        aoffE[ti] = (m0 + wm * 64 + ti * 16 + l15) * 40L;

    l2_panel<2>(Ax, aoffE, Wef2, 64, brow, 0, kq8, acc);  // Wef2 rows 33..63 zero

    #pragma unroll
    for (int ti = 0; ti < 4; ++ti) {
        #pragma unroll
        for (int r = 0; r < 4; ++r) {
            long mm = m0 + wm * 64 + ti * 16 + kq * 4 + r;
            #pragma unroll
            for (int tj = 0; tj < 4; ++tj)
                agf2[mm * Dd + n0w + tj * 16 + l15] = f2h(acc[ti][tj][r]);
        }
    }
}

// ---------------------------------------------------------------- layer-2 output aggregation
// out_pre[d] = agf2[d] + hsp[n] + sum_e ew*ht[ni]  (fp16, in place over agf2) + BN stats
__global__ __launch_bounds__(256) void k_out(const u16* __restrict__ ht,
                                             const u16* __restrict__ hsp,
                                             const int* __restrict__ base_end,
                                             const int* __restrict__ cnt,
                                             const int4* __restrict__ recs,
                                             u16* __restrict__ pre,
                                             float* __restrict__ stats) {
    __shared__ float sd[16][256];
    int gid = threadIdx.x >> 4;
    int gl = threadIdx.x & 15;
    int gl8 = gl * 8;
    float s[8] = {0, 0, 0, 0, 0, 0, 0, 0}, q[8] = {0, 0, 0, 0, 0, 0, 0, 0};
    for (long d = (long)blockIdx.x * 16 + gid; d < NR; d += (long)gridDim.x * 16) {
        int end = base_end[d];
        int c = cnt[d];
        int e = end - c;
        long n = d >> 3;
        short8 hv = *(const short8*)(hsp + n * Dd + gl8);
        short8 gv = *(const short8*)(pre + d * Dd + gl8);
        float a[8];
        #pragma unroll
        for (int j = 0; j < 8; ++j)
            a[j] = bf2f((u16)hv[j]) + h2f((u16)gv[j]);
        for (; e + 4 <= end; e += 4) {
            int4 r0 = recs[e],     r1 = recs[e + 1];
            int4 r2 = recs[e + 2], r3 = recs[e + 3];
            short8 x0 = *(const short8*)(ht + (long)r0.x * Dd + gl8);
            short8 x1 = *(const short8*)(ht + (long)r1.x * Dd + gl8);
            short8 x2 = *(const short8*)(ht + (long)r2.x * Dd + gl8);
            short8 x3 = *(const short8*)(ht + (long)r3.x * Dd + gl8);
            float w0 = __int_as_float(r0.y), w1 = __int_as_float(r1.y);
            float w2 = __int_as_float(r2.y), w3 = __int_as_float(r3.y);
            #pragma unroll
            for (int j = 0; j < 8; ++j) {
                a[j] = fmaf(w0, bf2f((u16)x0[j]), a[j]);
                a[j] = fmaf(w1, bf2f((u16)x1[j]), a[j]);
                a[j] = fmaf(w2, bf2f((u16)x2[j]), a[j]);
                a[j] = fmaf(w3, bf2f((u16)x3[j]), a[j]);
            }
        }
        if (e + 2 <= end) {
            int4 r0 = recs[e], r1 = recs[e + 1];
            short8 x0 = *(const short8*)(ht + (long)r0.x * Dd + gl8);
            short8 x1 = *(const short8*)(ht + (long)r1.x * Dd + gl8);
            float w0 = __int_as_float(r0.y), w1 = __int_as_float(r1.y);
            #pragma unroll
            for (int j = 0; j < 8; ++j) {
                a[j] = fmaf(w0, bf2f((u16)x0[j]), a[j]);
                a[j] = fmaf(w1, bf2f((u16)x1[j]), a[j]);
            }
            e += 2;
        }
        if (e < end) {
            int4 r0 = recs[e];
            float w0 = __int_as_float(r0.y);
            short8 x0 = *(const short8*)(ht + (long)r0.x * Dd + gl8);
            #pragma unroll
            for (int j = 0; j < 8; ++j)
                a[j] = fmaf(w0, bf2f((u16)x0[j]), a[j]);
        }
        short8 o;
        #pragma unroll
        for (int j = 0; j < 8; ++j) {
            o[j] = (short)f2h(a[j]);
            s[j] += a[j];
            q[j] = fmaf(a[j], a[j], q[j]);
        }
        *(short8*)(pre + d * Dd + gl8) = o;
    }
    #pragma unroll
    for (int j = 0; j < 8; ++j) {
        sd[gid][gl8 + j] = s[j];
        sd[gid][128 + gl8 + j] = q[j];
    }
    __syncthreads();
    int t = threadIdx.x;
    float acc = 0.f;
    #pragma unroll
    for (int g = 0; g < 16; ++g) acc += sd[g][t];
    unsafeAtomicAdd(stats + (blockIdx.x & (NREP - 1)) * 256 + t, acc);
}

// ---------------------------------------------------------------- BN apply + ReLU (bf16 in/out)
__global__ __launch_bounds__(256) void k_bn_apply_bf(u16* __restrict__ X,
                                                     const float* __restrict__ stats,
                                                     const float* __restrict__ g,
                                                     const float* __restrict__ b, int M) {
    int c = (threadIdx.x & 31) * 4;
    int rh = threadIdx.x >> 5;
    float invM = 1.0f / (float)M;
    float s[4] = {0, 0, 0, 0}, q[4] = {0, 0, 0, 0};
    for (int rep = 0; rep < NREP; ++rep) {
        float4 s4 = *(const float4*)(stats + rep * 256 + c);
        float4 q4 = *(const float4*)(stats + rep * 256 + 128 + c);
        s[0] += s4.x; s[1] += s4.y; s[2] += s4.z; s[3] += s4.w;
        q[0] += q4.x; q[1] += q4.y; q[2] += q4.z; q[3] += q4.w;
    }
    float4 g4 = *(const float4*)(g + c);
    float4 b4 = *(const float4*)(b + c);
    float gv[4] = {g4.x, g4.y, g4.z, g4.w};
    float bv[4] = {b4.x, b4.y, b4.z, b4.w};
    float sc[4], sh[4];
    #pragma unroll
    for (int j = 0; j < 4; ++j) {
        float m = s[j] * invM;
        sc[j] = gv[j] / sqrtf(q[j] * invM - m * m + BN_EPS);
        sh[j] = bv[j] - m * sc[j];
    }
    for (long r = blockIdx.x * 8 + rh; r < M; r += (long)gridDim.x * 8) {
        ushort4 v = *(ushort4*)(X + r * Dd + c);
        ushort4 o;
        o.x = f2bf(fmaxf(fmaf(bf2f(v.x), sc[0], sh[0]), 0.f));
        o.y = f2bf(fmaxf(fmaf(bf2f(v.y), sc[1], sh[1]), 0.f));
        o.z = f2bf(fmaxf(fmaf(bf2f(v.z), sc[2], sh[2]), 0.f));
        o.w = f2bf(fmaxf(fmaf(bf2f(v.w), sc[3], sh[3]), 0.f));
        *(ushort4*)(X + r * Dd + c) = o;
    }
}

// ---------------------------------------------------------------- BN apply + ReLU + permute (fp16 in, fp32 out)
// out[r*Nn+n] = relu(bn(pre[n*8+r]))
__global__ __launch_bounds__(256) void k_bn_out(const u16* __restrict__ pre,
                                                const float* __restrict__ stats,
                                                const float* __restrict__ g,
                                                const float* __restrict__ b,
                                                float* __restrict__ out) {
    int c = (threadIdx.x & 31) * 4;
    int rh = threadIdx.x >> 5;
    const float invM = 1.0f / (float)NR;
    float s[4] = {0, 0, 0, 0}, q[4] = {0, 0, 0, 0};
    for (int rep = 0; rep < NREP; ++rep) {
        float4 s4 = *(const float4*)(stats + rep * 256 + c);
        float4 q4 = *(const float4*)(stats + rep * 256 + 128 + c);
        s[0] += s4.x; s[1] += s4.y; s[2] += s4.z; s[3] += s4.w;
        q[0] += q4.x; q[1] += q4.y; q[2] += q4.z; q[3] += q4.w;
    }
    float4 g4 = *(const float4*)(g + c);
    float4 b4 = *(const float4*)(b + c);
    float gv[4] = {g4.x, g4.y, g4.z, g4.w};
    float bv[4] = {b4.x, b4.y, b4.z, b4.w};
    float sc[4], sh[4];
    #pragma unroll
    for (int j = 0; j < 4; ++j) {
        float m = s[j] * invM;
        sc[j] = gv[j] / sqrtf(q[j] * invM - m * m + BN_EPS);
        sh[j] = bv[j] - m * sc[j];
    }
    for (int m = blockIdx.x * 8 + rh; m < NR; m += gridDim.x * 8) {
        int r = m / Nn;
        int n = m - r * Nn;
        ushort4 v = *(const ushort4*)(pre + ((long)n * 8 + r) * Dd + c);
        float4 o;
        o.x = fmaxf(fmaf(h2f(v.x), sc[0], sh[0]), 0.f);
        o.y = fmaxf(fmaf(h2f(v.y), sc[1], sh[1]), 0.f);
        o.z = fmaxf(fmaf(h2f(v.z), sc[2], sh[2]), 0.f);
        o.w = fmaxf(fmaf(h2f(v.w), sc[3], sh[3]), 0.f);
        *(float4*)(out + (long)m * Dd + c) = o;
    }
}

// ---------------------------------------------------------------- launch
extern "C" void kernel_launch(void* const* d_in, const int* in_sizes, int n_in,
                              void* d_out, int out_size, void* d_ws, size_t ws_size,
                              hipStream_t stream) {
    const float* x            = (const float*)d_in[0];
    const int*   node_in      = (const int*)d_in[1];
    const int*   node_out     = (const int*)d_in[2];
    const int*   relation     = (const int*)d_in[3];
    const float* edge_weight  = (const float*)d_in[4];
    const float* edge_feature = (const float*)d_in[5];
    const float* l1_Wlin  = (const float*)d_in[6];
    const float* l1_Wself = (const float*)d_in[8];
    const float* l1_Wedge = (const float*)d_in[10];
    const float* l1_bedge = (const float*)d_in[11];
    const float* l1_g     = (const float*)d_in[12];
    const float* l1_b     = (const float*)d_in[13];
    const float* l2_Wlin  = (const float*)d_in[14];
    const float* l2_Wself = (const float*)d_in[16];
    const float* l2_Wedge = (const float*)d_in[18];
    const float* l2_bedge = (const float*)d_in[19];
    const float* l2_g     = (const float*)d_in[20];
    const float* l2_b     = (const float*)d_in[21];
    float* out = (float*)d_out;

    // workspace layout (~193 MB, heavy aliasing)
    u16* u_bf    = (u16*)d_ws;                        // NR*128 bf16; later agf2/out_pre fp16
    u16* h       = u_bf + (long)NR * Dd;              // Nn*128 bf16
    u16* x_bf    = h + (long)Nn * Dd;                 // Nn*128 bf16; later ht
    u16* aggef_x = x_bf + (long)Nn * Dd;              // NR*40 bf16 (+128 slack); later hsp
    u16* Bt      = aggef_x + (long)NR * 40 + 128;     // 11*16384 bf16
    u16* Wef1    = Bt + 11 * 16384;                   // 3*16384 bf16
    u16* Wef2    = Wef1 + 3 * 16384;                  // 8192 bf16
    float* deg   = (float*)(Wef2 + 8192);             // NR
    int*   cnt   = (int*)(deg + NR);                  // NR
    int*   base  = cnt + NR;                          // NR
    int4*  recs  = (int4*)(base + NR);                // Ee int4
    int*   partials = (int*)(recs + Ee);              // 1024
    float* stats = (float*)(partials + 1024);         // 2*NREP*256
    u16* agf2 = u_bf;                                 // alias (u dead after gemm_l1)
    u16* ht   = x_bf;                                 // alias (x_bf dead after gemm_l1)
    u16* hsp  = aggef_x;                              // alias (aggef_x dead after gemm_agf2)

    const int NB1 = (NR + 1023) / 1024;               // 391

    // ---- prep
    hipMemsetAsync(deg, 0, sizeof(float) * NR, stream);
    hipMemsetAsync(cnt, 0, sizeof(int) * NR, stream);
    hipMemsetAsync(stats, 0, sizeof(float) * 2 * NREP * 256, stream);
    hipMemsetAsync(aggef_x + (long)NR * 40, 0, 256, stream);  // slack read by agf2 tail
    k_deg<<<(Ee + 255) / 256, 256, 0, stream>>>(node_out, relation, edge_weight, deg, cnt);
    k_scan1<<<NB1, 256, 0, stream>>>(cnt, base, partials);
    k_scan2<<<1, 512, 0, stream>>>(partials, NB1);
    k_scan3<<<NB1, 256, 0, stream>>>(base, partials);
    k_scatter<<<(Ee + 255) / 256, 256, 0, stream>>>(node_in, node_out, relation, edge_weight,
                                                    deg, base, recs);
    k_cvt<<<((long)Nn * Dd / 4 + 255) / 256, 256, 0, stream>>>(x, x_bf, (long)Nn * Dd);
    k_prepB<<<(11 * 16384 + 255) / 256, 256, 0, stream>>>(l1_Wlin, l1_Wself, l2_Wlin, l2_Wself, Bt);
    k_prepWef1<<<(3 * 16384 + 255) / 256, 256, 0, stream>>>(l1_Wedge, l1_bedge, l1_Wlin, Wef1);
    k_prepWef2<<<32, 256, 0, stream>>>(l2_Wedge, l2_bedge, l2_Wlin, Wef2);

    // ---- layer 1
    k_agg1<<<4096, 256, 0, stream>>>(x_bf, base, cnt, recs, edge_feature, u_bf, aggef_x);
    k_gemm_l1<<<(Nn + 63) / 64, 256, 0, stream>>>(u_bf, x_bf, Bt, Wef1, aggef_x, h, stats);
    k_bn_apply_bf<<<512, 256, 0, stream>>>(h, stats, l1_g, l1_b, Nn);

    // ---- layer 2 (transform-then-aggregate; no big GEMM)
    k_gemm_agf2<<<NR / 128, 256, 0, stream>>>(aggef_x, Wef2, agf2);
    k_gemm_ht<<<(Nn + 63) / 64, 256, 0, stream>>>(h, Bt, ht, hsp);
    k_out<<<2048, 256, 0, stream>>>(ht, hsp, base, cnt, recs, agf2, stats + NREP * 256);
    k_bn_out<<<2048, 256, 0, stream>>>(agf2, stats + NREP * 256, l2_g, l2_b, out);
}